// Round 3
// baseline (289.559 us; speedup 1.0000x reference)
//
#include <hip/hip_runtime.h>
#include <hip/hip_bf16.h>
#include <cstdint>
#include <cstddef>

#define NROWS   32768
#define DIM     1024
#define NH      4
#define HD      256
#define NK      64
#define RPB     16              // rows per tile = one MFMA M-tile
#define TPB     4               // tiles per persistent block
#define PBLK    (NROWS / (RPB * TPB))   // 512 persistent blocks (2/CU)
#define THREADS 1024            // 16 waves: 1 row/wave (A,C), (head,tile) (B)

typedef __attribute__((ext_vector_type(8))) short short8;   // 8 bf16
typedef __attribute__((ext_vector_type(4))) float float4a;  // MFMA acc
typedef __attribute__((ext_vector_type(4))) float f32x4;    // for NT stores

__device__ __forceinline__ unsigned short f2bf(float f) {
  unsigned int u = __float_as_uint(f);
  u += 0x7fffu + ((u >> 16) & 1u);   // RNE (no NaN inputs here)
  return (unsigned short)(u >> 16);
}
__device__ __forceinline__ unsigned int pk2bf(float a, float b) {
  __hip_bfloat162 h = __float22bfloat162_rn(make_float2(a, b));  // v_cvt_pk_bf16_f32
  return *reinterpret_cast<unsigned int*>(&h);
}
__device__ __forceinline__ float bflo(unsigned int u) {
  return __uint_as_float(u << 16);
}
__device__ __forceinline__ float bfhi(unsigned int u) {
  return __uint_as_float(u & 0xffff0000u);
}
__device__ __forceinline__ void ntst(float* p, float4 v) {
  __builtin_nontemporal_store(*reinterpret_cast<f32x4*>(&v),
                              reinterpret_cast<f32x4*>(p));
}

// ---------------------------------------------------------------------------
// Pre-kernel: emb fp32 [4][64][256] -> bf16 B-fragment-linear layout in ws.
// granule g = ((h*4 + t)*8 + s)*64 + lane holds 8 bf16:
//   emb[h][t*16 + (lane&15)][s*32 + (lane>>4)*8 + 0..7]
// ---------------------------------------------------------------------------
__global__ __launch_bounds__(256) void vq_pre(const float* __restrict__ emb,
                                              unsigned short* __restrict__ ws_emb) {
  const int gid  = blockIdx.x * 256 + threadIdx.x;   // 0..8191
  const int lane = gid & 63;
  const int w    = gid >> 6;                          // (h*4 + t)*8 + s
  const int s = w & 7, ht = w >> 3, t = ht & 3, h = ht >> 2;
  const int code = t * 16 + (lane & 15);
  const int d0   = s * 32 + (lane >> 4) * 8;
  const float* p = emb + ((size_t)(h * NK + code)) * HD + d0;
  unsigned int w0 = f2bf(p[0]) | ((unsigned int)f2bf(p[1]) << 16);
  unsigned int w1 = f2bf(p[2]) | ((unsigned int)f2bf(p[3]) << 16);
  unsigned int w2 = f2bf(p[4]) | ((unsigned int)f2bf(p[5]) << 16);
  unsigned int w3 = f2bf(p[6]) | ((unsigned int)f2bf(p[7]) << 16);
  uint4 pk = make_uint4(w0, w1, w2, w3);
  *(uint4*)(ws_emb + (size_t)(w * 64 + lane) * 8) = pk;
}

// ---------------------------------------------------------------------------
// Main kernel: 512 persistent blocks x 4 tiles of 16 rows. Rolling prefetch:
// tile t+1's row loads are issued inside tile t's Phase A as each chunk is
// consumed, so 4 KB/wave is in flight across B/C and the barriers.
// ---------------------------------------------------------------------------
__global__ __launch_bounds__(THREADS, 8) void vq_main(
    const float* __restrict__ in, const float* __restrict__ lnw,
    const float* __restrict__ lnb, const float* __restrict__ emb,
    const unsigned short* __restrict__ ws_emb,
    float* __restrict__ out, float* __restrict__ ws)
{
  // x tile, bf16, fragment-swizzled: granule ((h*8+s)*4+q)*16 + (m^(q<<2)^s)
  __shared__ __align__(16) unsigned short xs[NH * 8 * 4 * 16 * 8]; // 32 KB
  __shared__ __align__(16) unsigned short wsh[DIM];  // ln weight, bf16 (2 KB)
  __shared__ __align__(16) unsigned short bsh[DIM];  // ln bias,   bf16 (2 KB)
  __shared__ float inv_s[RPB];
  __shared__ float base_s[RPB];                  // 4 + ssx*inv^2
  __shared__ __align__(16) int bidx_s[RPB][NH];
  __shared__ float bval_s[RPB][NH];
  __shared__ float cva[RPB][NH][4];              // per (row,head) candidates
  __shared__ int   cia[RPB][NH][4];
  __shared__ unsigned long long ms4[NH];

  float* ws_loss = ws;                                             // [PBLK]
  unsigned long long* ws_mask = (unsigned long long*)(ws + PBLK);  // [PBLK]

  const int tid  = threadIdx.x;
  const int wave = tid >> 6;      // 0..15
  const int lane = tid & 63;
  const int m    = wave;          // this wave's row within a tile

  // ---- stage LN weight/bias to LDS as bf16 (once) ----
  if (tid < 256) {
    float4 w4 = *(const float4*)(lnw + tid * 4);
    float4 b4 = *(const float4*)(lnb + tid * 4);
    uint2 wp, bp;
    wp.x = pk2bf(w4.x, w4.y); wp.y = pk2bf(w4.z, w4.w);
    bp.x = pk2bf(b4.x, b4.y); bp.y = pk2bf(b4.z, b4.w);
    *(uint2*)&wsh[tid * 4] = wp;
    *(uint2*)&bsh[tid * 4] = bp;
  }

  const size_t row_base = (size_t)blockIdx.x * (RPB * TPB) + m;

  // prefetch tile 0 (in flight during weight-staging barrier)
  float4 vn[4];
  {
    const float* rp = in + row_base * DIM;
    #pragma unroll
    for (int c = 0; c < 4; ++c) vn[c] = *(const float4*)(rp + c * 256 + lane * 4);
  }
  __syncthreads();

  const int sA = lane >> 3;          // k-step of this lane's dims
  const int qA = (lane >> 1) & 3;    // k-octet quad
  const int hfA = lane & 1;          // low/high half of octet
  const int msw = m ^ (qA << 2) ^ sA;

  float lacc = 0.f;                  // per-block loss accumulator (wave 0)
  unsigned long long pres = 0ull;    // per-head presence accumulator (waves 0-3)

  for (int t = 0; t < TPB; ++t) {
    // ---------------- Phase A: LN + soft-clip, 1 row per wave ---------------
    float s1 = 0.f, s2 = 0.f;
    #pragma unroll
    for (int c = 0; c < 4; ++c) {
      s1 += (vn[c].x + vn[c].y) + (vn[c].z + vn[c].w);
      s2 = fmaf(vn[c].x, vn[c].x, s2); s2 = fmaf(vn[c].y, vn[c].y, s2);
      s2 = fmaf(vn[c].z, vn[c].z, s2); s2 = fmaf(vn[c].w, vn[c].w, s2);
    }
    #pragma unroll
    for (int d = 1; d < 64; d <<= 1) {
      s1 += __shfl_xor(s1, d, 64);
      s2 += __shfl_xor(s2, d, 64);
    }
    const float mu   = s1 * (1.0f / 1024.0f);
    const float var  = fmaf(-mu, mu, s2 * (1.0f / 1024.0f));
    const float rstd = rsqrtf(var + 1e-5f);
    const float nmu  = -mu * rstd;            // xh = fma(x, rstd, nmu)

    const float* nrp = in + (row_base + (size_t)(t + 1) * RPB) * DIM;

    float ss = 0.f;
    #pragma unroll
    for (int c = 0; c < 4; ++c) {
      const uint2 wu = *(const uint2*)&wsh[c * 256 + lane * 4];
      const uint2 bu = *(const uint2*)&bsh[c * 256 + lane * 4];
      const float wf[4] = { bflo(wu.x), bfhi(wu.x), bflo(wu.y), bfhi(wu.y) };
      const float bf[4] = { bflo(bu.x), bfhi(bu.x), bflo(bu.y), bfhi(bu.y) };
      const float4 vv = vn[c];
      const float pv[4] = { vv.x, vv.y, vv.z, vv.w };
      float xx[4];
      #pragma unroll
      for (int i = 0; i < 4; ++i) {
        float xh = fmaf(pv[i], rstd, nmu);
        xh = fmaf(xh, wf[i], bf[i]);
        // 5*tanh(xh/5) = 5 - 10/(exp2(xh*0.4*log2e)+1)
        const float e = exp2f(xh * 0.57707801635f);
        const float r = __builtin_amdgcn_rcpf(e + 1.f);
        const float x = fmaf(-10.f, r, 5.f);
        ss = fmaf(x, x, ss);
        xx[i] = x;
      }
      // store bf16 A-fragments (swizzled), chunk c
      const int gran = ((c * 8 + sA) * 4 + qA) * 16 + msw;
      uint2 pk;
      pk.x = pk2bf(xx[0], xx[1]);
      pk.y = pk2bf(xx[2], xx[3]);
      *(uint2*)&xs[gran * 8 + hfA * 4] = pk;
      // chunk consumed -> issue next tile's load for this chunk (rolling)
      if (t + 1 < TPB) vn[c] = *(const float4*)(nrp + c * 256 + lane * 4);
    }
    #pragma unroll
    for (int d = 1; d < 64; d <<= 1) ss += __shfl_xor(ss, d, 64);

    if (lane == 0) {
      const float nrm = sqrtf(ss);
      const float iv  = 1.f / fmaxf(nrm, 1e-5f);
      inv_s[m]  = iv;
      base_s[m] = fmaf(ss * iv, iv, 4.f);   // ||q||^2(=4) + ||xn||^2
    }
    __syncthreads();                        // (1) xs / inv_s ready

    // ---------------- Phase B: MFMA distances + per-wave argmax -------------
    {
      const int h = wave >> 2, tt = wave & 3;   // head, code tile
      const int q = lane >> 4, mm = lane & 15;
      const short8* eb = (const short8*)ws_emb + (size_t)h * 2048 + lane;

      float4a acc;
      #pragma unroll
      for (int r = 0; r < 4; ++r) acc[r] = 0.f;
      #pragma unroll
      for (int s = 0; s < 8; ++s) {           // streamed: low VGPR pressure
        const int gran = (h * 8 + s) * 64 + q * 16 + (mm ^ (q << 2) ^ s);
        const short8 a = *(const short8*)&xs[gran * 8];
        const short8 b = eb[(tt * 8 + s) * 64];
        acc = __builtin_amdgcn_mfma_f32_16x16x32_bf16(a, b, acc, 0, 0, 0);
      }

      // acc[r] = dist[row=q*4+r][code=tt*16+mm]
      #pragma unroll
      for (int r = 0; r < 4; ++r) {
        float bv = acc[r];
        int   bi = tt * 16 + mm;
        #pragma unroll
        for (int d = 1; d <= 8; d <<= 1) {
          const float ov = __shfl_xor(bv, d, 64);
          const int   oi = __shfl_xor(bi, d, 64);
          if (ov > bv || (ov == bv && oi < bi)) { bv = ov; bi = oi; }
        }
        if (mm == 0) {
          const int row = q * 4 + r;
          cva[row][h][tt] = bv;
          cia[row][h][tt] = bi;
        }
      }
    }
    __syncthreads();                        // (2) candidates ready

    // -------------- Combine the 4 candidates per (row, head) ---------------
    if (tid < 64) {
      const int row = tid >> 2, h = tid & 3;
      // ascending-index order; strict > keeps lowest index on ties
      float wv = cva[row][h][0];
      int   win = cia[row][h][0];
      #pragma unroll
      for (int k = 1; k < 4; ++k) {
        const float v1 = cva[row][h][k];
        const int   i1 = cia[row][h][k];
        if (v1 > wv) { wv = v1; win = i1; }
      }
      bidx_s[row][h] = win;
      bval_s[row][h] = wv;
    }
    __syncthreads();                        // (3) bidx/bval ready

    // -------------- Phase C: gather-write q; loss; presence -----------------
    {
      const int4 bi = *(const int4*)(&bidx_s[m][0]);
      const float4 q0 = *(const float4*)(emb + (size_t)(0 * NK + bi.x) * HD + lane * 4);
      const float4 q1 = *(const float4*)(emb + (size_t)(1 * NK + bi.y) * HD + lane * 4);
      const float4 q2 = *(const float4*)(emb + (size_t)(2 * NK + bi.z) * HD + lane * 4);
      const float4 q3 = *(const float4*)(emb + (size_t)(3 * NK + bi.w) * HD + lane * 4);
      float* op = out + (row_base + (size_t)t * RPB) * DIM + lane * 4;
      ntst(op + 0,   q0);                   // NT: output never re-read;
      ntst(op + 256, q1);                   // keep LLC for the input stream
      ntst(op + 512, q2);
      ntst(op + 768, q3);
    }

    if (wave == 0 && lane < RPB) {
      const float ds = (bval_s[lane][0] + bval_s[lane][1]) +
                       (bval_s[lane][2] + bval_s[lane][3]);
      lacc += fmaf(-2.f * inv_s[lane], ds, base_s[lane]);
    }
    if (wave < 4) {
      int f = 0;
      #pragma unroll
      for (int r = 0; r < RPB; ++r) f |= (bidx_s[r][wave] == lane) ? 1 : 0;
      pres |= __ballot(f != 0);
    }
    __syncthreads();                        // (4) guard next tile's overwrites
  }

  // ---------------- epilogue: one write per block ---------------------------
  if (wave == 0) {
    #pragma unroll
    for (int d = 1; d <= 8; d <<= 1) lacc += __shfl_xor(lacc, d, 64);
    if (lane == 0) ws_loss[blockIdx.x] = lacc;
  }
  if (wave < 4 && lane == 0) ms4[wave] = pres;
  __syncthreads();
  if (tid == 0) ws_mask[blockIdx.x] = ms4[0] | ms4[1] | ms4[2] | ms4[3];
}

__global__ __launch_bounds__(256) void vq_fin(const float* __restrict__ ws,
                                              float* __restrict__ out) {
  __shared__ float ls[4];
  __shared__ unsigned long long ms[4];
  const float* ws_loss = ws;
  const unsigned long long* ws_mask = (const unsigned long long*)(ws + PBLK);

  const int tid = threadIdx.x, wave = tid >> 6, lane = tid & 63;
  float l = 0.f;
  unsigned long long m = 0ull;
  for (int i = tid; i < PBLK; i += 256) { l += ws_loss[i]; m |= ws_mask[i]; }
  #pragma unroll
  for (int s = 1; s < 64; s <<= 1) {
    l += __shfl_xor(l, s, 64);
    m |= __shfl_xor(m, s, 64);
  }
  if (lane == 0) { ls[wave] = l; ms[wave] = m; }
  __syncthreads();
  if (tid == 0) {
    const float total = (ls[0] + ls[1]) + (ls[2] + ls[3]);
    const unsigned long long mm = ms[0] | ms[1] | ms[2] | ms[3];
    out[33554432] = 0.25f * total / 33554432.0f;
    out[33554433] = (float)__popcll(mm);
  }
}

extern "C" void kernel_launch(void* const* d_in, const int* in_sizes, int n_in,
                              void* d_out, int out_size, void* d_ws, size_t ws_size,
                              hipStream_t stream) {
  const float* in  = (const float*)d_in[0];
  const float* lnw = (const float*)d_in[1];
  const float* lnb = (const float*)d_in[2];
  const float* emb = (const float*)d_in[3];
  float* out = (float*)d_out;
  float* ws  = (float*)d_ws;

  // ws layout: [0,512) loss floats | [512, 512+1024) mask u64s |
  //            byte offset 24576: emb bf16 fragments (131072 B)
  unsigned short* ws_emb = (unsigned short*)((char*)d_ws + 24576);

  vq_pre<<<32, 256, 0, stream>>>(emb, ws_emb);
  vq_main<<<PBLK, THREADS, 0, stream>>>(in, lnw, lnb, emb, ws_emb, out, ws);
  vq_fin<<<1, 256, 0, stream>>>(ws, out);
}

// Round 5
// 249.600 us; speedup vs baseline: 1.1601x; 1.1601x over previous
//
#include <hip/hip_runtime.h>
#include <hip/hip_bf16.h>
#include <cstdint>
#include <cstddef>

#define NROWS   32768
#define DIM     1024
#define NH      4
#define HD      256
#define NK      64
#define RPB     16           // rows per block = one MFMA M-tile
#define NBLK    (NROWS / RPB)   // 2048
#define THREADS 1024         // 16 waves: 1 row/wave (A,C), (head,tile) (B)

typedef __attribute__((ext_vector_type(8))) short short8;   // 8 bf16
typedef __attribute__((ext_vector_type(4))) float float4a;  // MFMA acc

__device__ __forceinline__ unsigned short f2bf(float f) {
  unsigned int u = __float_as_uint(f);
  u += 0x7fffu + ((u >> 16) & 1u);   // RNE (no NaN inputs here)
  return (unsigned short)(u >> 16);
}
__device__ __forceinline__ unsigned int pk2bf(float a, float b) {
  __hip_bfloat162 h = __float22bfloat162_rn(make_float2(a, b));  // v_cvt_pk_bf16_f32
  return *reinterpret_cast<unsigned int*>(&h);
}
__device__ __forceinline__ float bflo(unsigned int u) {
  return __uint_as_float(u << 16);
}
__device__ __forceinline__ float bfhi(unsigned int u) {
  return __uint_as_float(u & 0xffff0000u);
}

// ---- DPP wave reduction (VALU-only, no LDS pipe) --------------------------
// ctrl must be a literal -> template parameters.
// row_shr:k = 0x110|k, row_bcast15 = 0x142, row_bcast31 = 0x143
template <int CTRL, int RM>
__device__ __forceinline__ float dpp_add0(float x) {
  int t = __builtin_amdgcn_update_dpp(0, __float_as_int(x), CTRL, RM, 0xf, true);
  return x + __int_as_float(t);
}
// full 64-lane sum, result uniform in all lanes
__device__ __forceinline__ float wave_sum(float x) {
  x = dpp_add0<0x111, 0xf>(x);
  x = dpp_add0<0x112, 0xf>(x);
  x = dpp_add0<0x114, 0xf>(x);
  x = dpp_add0<0x118, 0xf>(x);
  x = dpp_add0<0x142, 0xa>(x);   // row_bcast:15 into rows 1,3
  x = dpp_add0<0x143, 0xc>(x);   // row_bcast:31 into rows 2,3; lane63 = total
  return __int_as_float(__builtin_amdgcn_readlane(__float_as_int(x), 63));
}
// one (val,idx) DPP max step; invalid lanes keep their own candidate
template <int CTRL>
__device__ __forceinline__ void dpp_argmax_step(float& bv, int& bi) {
  const float ov = __int_as_float(__builtin_amdgcn_update_dpp(
      __float_as_int(bv), __float_as_int(bv), CTRL, 0xf, 0xf, false));
  const int oi = __builtin_amdgcn_update_dpp(bi, bi, CTRL, 0xf, 0xf, false);
  if (ov > bv || (ov == bv && oi < bi)) { bv = ov; bi = oi; }
}
// argmax over each 16-lane row; result valid in lane 15 of each row;
// ties -> lowest index (incoming candidate always has lower lane -> lower idx)
__device__ __forceinline__ void row16_argmax(float& bv, int& bi) {
  dpp_argmax_step<0x111>(bv, bi);   // row_shr:1
  dpp_argmax_step<0x112>(bv, bi);   // row_shr:2
  dpp_argmax_step<0x114>(bv, bi);   // row_shr:4
  dpp_argmax_step<0x118>(bv, bi);   // row_shr:8
}
// max+idx butterfly within each quad (all 4 lanes end with the result)
__device__ __forceinline__ void quad4_argmax(float& bv, int& bi) {
  dpp_argmax_step<0xB1>(bv, bi);    // quad_perm [1,0,3,2]
  dpp_argmax_step<0x4E>(bv, bi);    // quad_perm [2,3,0,1]
}

// ---------------------------------------------------------------------------
// Pre-kernel: emb fp32 [4][64][256] -> bf16 B-fragment-linear layout in ws.
// ---------------------------------------------------------------------------
__global__ __launch_bounds__(256) void vq_pre(const float* __restrict__ emb,
                                              unsigned short* __restrict__ ws_emb) {
  const int gid  = blockIdx.x * 256 + threadIdx.x;   // 0..8191
  const int lane = gid & 63;
  const int w    = gid >> 6;                          // (h*4 + t)*8 + s
  const int s = w & 7, ht = w >> 3, t = ht & 3, h = ht >> 2;
  const int code = t * 16 + (lane & 15);
  const int d0   = s * 32 + (lane >> 4) * 8;
  const float* p = emb + ((size_t)(h * NK + code)) * HD + d0;
  unsigned int w0 = f2bf(p[0]) | ((unsigned int)f2bf(p[1]) << 16);
  unsigned int w1 = f2bf(p[2]) | ((unsigned int)f2bf(p[3]) << 16);
  unsigned int w2 = f2bf(p[4]) | ((unsigned int)f2bf(p[5]) << 16);
  unsigned int w3 = f2bf(p[6]) | ((unsigned int)f2bf(p[7]) << 16);
  uint4 pk = make_uint4(w0, w1, w2, w3);
  *(uint4*)(ws_emb + (size_t)(w * 64 + lane) * 8) = pk;
}

// ---------------------------------------------------------------------------
// Main kernel, 1024 threads (16 waves), 16 rows/block (Round-2 structure,
// all shuffle reductions moved to DPP on the VALU).
// ---------------------------------------------------------------------------
__global__ __launch_bounds__(THREADS, 8) void vq_main(
    const float* __restrict__ in, const float* __restrict__ lnw,
    const float* __restrict__ lnb, const float* __restrict__ emb,
    const unsigned short* __restrict__ ws_emb,
    float* __restrict__ out, float* __restrict__ ws)
{
  // x tile, bf16, fragment-swizzled: granule ((h*8+s)*4+q)*16 + (m^(q<<2)^s)
  __shared__ __align__(16) unsigned short xs[NH * 8 * 4 * 16 * 8]; // 32 KB
  __shared__ __align__(16) unsigned short wsh[DIM];  // ln weight, bf16 (2 KB)
  __shared__ __align__(16) unsigned short bsh[DIM];  // ln bias,   bf16 (2 KB)
  __shared__ int flags_s[NH][NK];                // per-head present flags
  __shared__ float cva[RPB][NH][4];              // per (row,head) candidates
  __shared__ int   cia[RPB][NH][4];
  __shared__ float rl_s[RPB];                    // per-row loss

  float* ws_loss = ws;                                             // [NBLK]
  unsigned long long* ws_mask = (unsigned long long*)(ws + NBLK);  // [NBLK]

  const int tid  = threadIdx.x;
  const int wave = tid >> 6;      // 0..15
  const int lane = tid & 63;
  const int row0 = blockIdx.x * RPB;
  const int m    = wave;          // this wave's row

  // ---- weight loads first, then input prefetch, then staging ----
  float4 w4, b4;
  if (tid < 256) {
    w4 = *(const float4*)(lnw + tid * 4);
    b4 = *(const float4*)(lnb + tid * 4);
  }

  float4 v[4];
  {
    const float* rp = in + (size_t)(row0 + m) * DIM;
    #pragma unroll
    for (int c = 0; c < 4; ++c) v[c] = *(const float4*)(rp + c * 256 + lane * 4);
  }

  if (tid < 256) {
    flags_s[tid >> 6][tid & 63] = 0;   // 256 ints
    uint2 wp, bp;
    wp.x = pk2bf(w4.x, w4.y); wp.y = pk2bf(w4.z, w4.w);
    bp.x = pk2bf(b4.x, b4.y); bp.y = pk2bf(b4.z, b4.w);
    *(uint2*)&wsh[tid * 4] = wp;
    *(uint2*)&bsh[tid * 4] = bp;
  }
  __syncthreads();                          // (0) weights staged

  // ---------------- Phase A: LN + soft-clip, 1 row per wave -----------------
  const int sA = lane >> 3;          // k-step of this lane's dims
  const int qA = (lane >> 1) & 3;    // k-octet quad
  const int hfA = lane & 1;          // low/high half of octet
  const int msw = m ^ (qA << 2) ^ sA;

  float s1 = 0.f, s2 = 0.f;
  #pragma unroll
  for (int c = 0; c < 4; ++c) {
    s1 += (v[c].x + v[c].y) + (v[c].z + v[c].w);
    s2 = fmaf(v[c].x, v[c].x, s2); s2 = fmaf(v[c].y, v[c].y, s2);
    s2 = fmaf(v[c].z, v[c].z, s2); s2 = fmaf(v[c].w, v[c].w, s2);
  }
  s1 = wave_sum(s1);
  s2 = wave_sum(s2);
  const float mu   = s1 * (1.0f / 1024.0f);
  const float var  = fmaf(-mu, mu, s2 * (1.0f / 1024.0f));
  const float rstd = rsqrtf(var + 1e-5f);
  const float nmu  = -mu * rstd;            // xh = fma(x, rstd, nmu)

  float ss = 0.f;
  #pragma unroll
  for (int c = 0; c < 4; ++c) {
    const uint2 wu = *(const uint2*)&wsh[c * 256 + lane * 4];
    const uint2 bu = *(const uint2*)&bsh[c * 256 + lane * 4];
    const float wf[4] = { bflo(wu.x), bfhi(wu.x), bflo(wu.y), bfhi(wu.y) };
    const float bf[4] = { bflo(bu.x), bfhi(bu.x), bflo(bu.y), bfhi(bu.y) };
    float* pv = reinterpret_cast<float*>(&v[c]);
    float xx[4];
    #pragma unroll
    for (int i = 0; i < 4; ++i) {
      float xh = fmaf(pv[i], rstd, nmu);
      xh = fmaf(xh, wf[i], bf[i]);
      // 5*tanh(xh/5) = 5 - 10/(exp2(xh*0.4*log2e)+1)
      const float e = exp2f(xh * 0.57707801636f);
      const float r = __builtin_amdgcn_rcpf(e + 1.f);
      const float x = fmaf(-10.f, r, 5.f);
      ss = fmaf(x, x, ss);
      xx[i] = x;
    }
    const int gran = ((c * 8 + sA) * 4 + qA) * 16 + msw;
    uint2 pk;
    pk.x = pk2bf(xx[0], xx[1]);
    pk.y = pk2bf(xx[2], xx[3]);
    *(uint2*)&xs[gran * 8 + hfA * 4] = pk;
  }
  ss = wave_sum(ss);

  // per-row scalars stay in registers (wave m owns row m in Phase C too)
  const float nrm  = sqrtf(ss);
  const float iv   = 1.f / fmaxf(nrm, 1e-5f);
  const float base = fmaf(ss * iv, iv, 4.f);   // ||q||^2(=4) + ||xn||^2
  __syncthreads();                          // (1) xs ready

  // ---------------- Phase B: MFMA distances + DPP argmax --------------------
  {
    const int h = wave >> 2, tt = wave & 3;   // head, code tile
    const int q = lane >> 4, mm = lane & 15;
    const short8* eb = (const short8*)ws_emb + (size_t)h * 2048 + lane;

    float4a acc;
    #pragma unroll
    for (int r = 0; r < 4; ++r) acc[r] = 0.f;
    #pragma unroll
    for (int s = 0; s < 8; ++s) {
      const int gran = (h * 8 + s) * 64 + q * 16 + (mm ^ (q << 2) ^ s);
      const short8 a = *(const short8*)&xs[gran * 8];
      const short8 b = eb[(tt * 8 + s) * 64];
      acc = __builtin_amdgcn_mfma_f32_16x16x32_bf16(a, b, acc, 0, 0, 0);
    }

    // acc[r] = dist[row=q*4+r][code=tt*16+mm]
    #pragma unroll
    for (int r = 0; r < 4; ++r) {
      float bv = acc[r];
      int   bi = tt * 16 + mm;
      row16_argmax(bv, bi);                 // valid in mm==15
      if (mm == 15) {
        const int row = q * 4 + r;
        cva[row][h][tt] = bv;
        cia[row][h][tt] = bi;
      }
    }
  }
  __syncthreads();                          // (2) candidates ready

  // ---------------- Phase C: combine + gather + loss + presence -------------
  {
    // lanes replicate j = lane&15: j>>2 = head, j&3 = candidate tile
    const int j = lane & 15;
    float bv = cva[m][j >> 2][j & 3];
    int   bi = cia[m][j >> 2][j & 3];
    quad4_argmax(bv, bi);                   // per-quad combined (all 4 lanes)

    const int b0 = __builtin_amdgcn_readlane(bi, 0);
    const int b1 = __builtin_amdgcn_readlane(bi, 4);
    const int b2 = __builtin_amdgcn_readlane(bi, 8);
    const int b3 = __builtin_amdgcn_readlane(bi, 12);

    const float4 q0 = *(const float4*)(emb + (size_t)(0 * NK + b0) * HD + lane * 4);
    const float4 q1 = *(const float4*)(emb + (size_t)(1 * NK + b1) * HD + lane * 4);
    const float4 q2 = *(const float4*)(emb + (size_t)(2 * NK + b2) * HD + lane * 4);
    const float4 q3 = *(const float4*)(emb + (size_t)(3 * NK + b3) * HD + lane * 4);
    float* op = out + (size_t)(row0 + m) * DIM + lane * 4;
    *(float4*)(op + 0)   = q0;
    *(float4*)(op + 256) = q1;
    *(float4*)(op + 512) = q2;
    *(float4*)(op + 768) = q3;

    const float v0 = __int_as_float(__builtin_amdgcn_readlane(__float_as_int(bv), 0));
    const float v1 = __int_as_float(__builtin_amdgcn_readlane(__float_as_int(bv), 4));
    const float v2 = __int_as_float(__builtin_amdgcn_readlane(__float_as_int(bv), 8));
    const float v3 = __int_as_float(__builtin_amdgcn_readlane(__float_as_int(bv), 12));
    const float ds = (v0 + v1) + (v2 + v3);
    if (lane == 0) rl_s[m] = fmaf(-2.f * iv, ds, base);
    if (lane < 16 && (lane & 3) == 0) flags_s[lane >> 2][bi] = 1;
  }
  __syncthreads();                          // (3) rl_s / flags ready

  if (wave == 0) {
    float l = (lane < RPB) ? rl_s[lane] : 0.f;
    l = wave_sum(l);
    if (lane == 0) ws_loss[blockIdx.x] = l;
  } else if (wave == 1) {
    const int f = flags_s[0][lane] | flags_s[1][lane] |
                  flags_s[2][lane] | flags_s[3][lane];
    const unsigned long long mk = __ballot(f != 0);
    if (lane == 0) ws_mask[blockIdx.x] = mk;
  }
}

__global__ __launch_bounds__(256) void vq_fin(const float* __restrict__ ws,
                                              float* __restrict__ out) {
  __shared__ float ls[4];
  __shared__ unsigned long long ms[4];
  const float* ws_loss = ws;
  const unsigned long long* ws_mask = (const unsigned long long*)(ws + NBLK);

  const int tid = threadIdx.x, wave = tid >> 6, lane = tid & 63;
  float l = 0.f;
  unsigned long long m = 0ull;
  for (int i = tid; i < NBLK; i += 256) { l += ws_loss[i]; m |= ws_mask[i]; }
  #pragma unroll
  for (int s = 1; s < 64; s <<= 1) {
    l += __shfl_xor(l, s, 64);
    m |= __shfl_xor(m, s, 64);
  }
  if (lane == 0) { ls[wave] = l; ms[wave] = m; }
  __syncthreads();
  if (tid == 0) {
    const float total = (ls[0] + ls[1]) + (ls[2] + ls[3]);
    const unsigned long long mm = ms[0] | ms[1] | ms[2] | ms[3];
    out[33554432] = 0.25f * total / 33554432.0f;
    out[33554433] = (float)__popcll(mm);
  }
}

extern "C" void kernel_launch(void* const* d_in, const int* in_sizes, int n_in,
                              void* d_out, int out_size, void* d_ws, size_t ws_size,
                              hipStream_t stream) {
  const float* in  = (const float*)d_in[0];
  const float* lnw = (const float*)d_in[1];
  const float* lnb = (const float*)d_in[2];
  const float* emb = (const float*)d_in[3];
  float* out = (float*)d_out;
  float* ws  = (float*)d_ws;

  // ws layout: [0,2048) loss floats | [2048, 2048+4096) mask u64s |
  //            byte offset 24576: emb bf16 fragments (131072 B)
  unsigned short* ws_emb = (unsigned short*)((char*)d_ws + 24576);

  vq_pre<<<32, 256, 0, stream>>>(emb, ws_emb);
  vq_main<<<NBLK, THREADS, 0, stream>>>(in, lnw, lnb, emb, ws_emb, out, ws);
  vq_fin<<<1, 256, 0, stream>>>(ws, out);
}